// Round 10
// baseline (806.714 us; speedup 1.0000x reference)
//
#include <hip/hip_runtime.h>

typedef __attribute__((ext_vector_type(8))) short short8;
typedef __attribute__((ext_vector_type(4))) short short4v;
typedef __attribute__((ext_vector_type(2))) unsigned int uint2v;
typedef __attribute__((ext_vector_type(4))) float floatx4;

__device__ __forceinline__ unsigned short f2bf(float f) {
    unsigned int u = __float_as_uint(f);
    u += 0x7FFFu + ((u >> 16) & 1u);   // round-to-nearest-even
    return (unsigned short)(u >> 16);
}
__device__ __forceinline__ float bf2f(unsigned short s) {
    return __uint_as_float(((unsigned int)s) << 16);
}
__device__ __forceinline__ float sigmoidf(float x) {
    return 1.f / (1.f + __expf(-x));
}
// RTNE f32x4 -> bf16x4 via v_cvt_pk_bf16_f32 (no builtin on gfx950; T12 notes)
__device__ __forceinline__ short4v pack4(floatx4 v) {
    unsigned int a, b;
    asm("v_cvt_pk_bf16_f32 %0, %1, %2" : "=v"(a) : "v"(v[0]), "v"(v[1]));
    asm("v_cvt_pk_bf16_f32 %0, %1, %2" : "=v"(b) : "v"(v[2]), "v"(v[3]));
    uint2v u; u[0] = a; u[1] = b;
    return __builtin_bit_cast(short4v, u);
}

// Wf|Wa fp32 [256,512] -> bf16, MFMA A-operand fragment order (R8 layout).
// short8 idx = (g*16 + ks)*64 + lane; lane slot lk*16+l15 holds
// W[d = g*16+l15][k = ks*32+lk*8 .. +8].  g<16 -> Wf, g>=16 -> Wa.
__global__ __launch_bounds__(256)
void convert_w_kernel(const float* __restrict__ Wf,
                      const float* __restrict__ Wa,
                      short* __restrict__ wswz)
{
    int id = blockIdx.x * 256 + threadIdx.x;       // 32768 total
    int slot = id & 63;
    int ks   = (id >> 6) & 15;
    int g    = id >> 10;
    int l15  = slot & 15, lk = slot >> 4;
    const float* base = (g < 16) ? (Wf + (long)(g * 16 + l15) * 512)
                                 : (Wa + (long)((g - 16) * 16 + l15) * 512);
    const float* src = base + ks * 32 + lk * 8;
    floatx4 w0 = *(const floatx4*)src;
    floatx4 w1 = *(const floatx4*)(src + 4);
    short8 o;
    o[0] = (short)f2bf(w0[0]); o[1] = (short)f2bf(w0[1]);
    o[2] = (short)f2bf(w0[2]); o[3] = (short)f2bf(w0[3]);
    o[4] = (short)f2bf(w1[0]); o[5] = (short)f2bf(w1[1]);
    o[6] = (short)f2bf(w1[2]); o[7] = (short)f2bf(w1[3]);
    *(short8*)(wswz + (long)id * 8) = o;
}

__global__ __launch_bounds__(256)
void zero_inv_kernel(int* __restrict__ inv)        // 262144 ints
{
    inv[blockIdx.x * 256 + threadIdx.x] = 0;
}

// inv[row] = symbol_idx + 1 (0 = row not updated). Occurrence rows unique.
__global__ __launch_bounds__(256)
void scatter_inv_kernel(const int* __restrict__ ei, const int* __restrict__ ti,
                        const int* __restrict__ si, int* __restrict__ inv, int n)
{
    int i = blockIdx.x * 256 + threadIdx.x;
    if (i < n) inv[64 * ei[i] + ti[i]] = si[i] + 1;
}

// Streaming fused kernel over ALL rows (no random prev-gather, no copy pass).
// 512 blocks x 8 tiles, tile = 64 consecutive rows, 512 thr (8 waves),
// LDS: P[64][256] bf16 + U[64][256] bf16 (chunk ^= row&7 swizzle) + flg.
// Per tile:
//   stage: U-loads (random, syms L2/L3-hot) issued first; P converted from
//          regs PREFETCHED under the previous tile's GEMM (coalesced stream);
//          cvt_pk packing. Staging writes are full-row permutations (<=2-way).
//   GEMM:  K=512 (ks<8 from P, ks>=8 from U), A=weights from L2 (R8 layout),
//          acc[4][4]; wave w owns d in [32w,32w+32) for both gates.
//   combine: flagged lanes only, in-place bf16 into P slots.
//   store: every row, full 1KB contiguous dwordx4 -> pure write stream.
__global__ __launch_bounds__(512, 4)
void stream_kernel(const float* __restrict__ flat,   // [262144,256]
                   const float* __restrict__ syms,   // [20000,256]
                   const float* __restrict__ bfb,
                   const float* __restrict__ bab,
                   const int* __restrict__ inv,
                   const short* __restrict__ wswz,
                   float* __restrict__ out, int tiles_per_block)
{
    __shared__ __align__(16) short P[64 * 256];   // 32 KB
    __shared__ __align__(16) short U[64 * 256];   // 32 KB
    __shared__ int flg[64];

    const int tid  = threadIdx.x;
    const int lane = tid & 63, w = tid >> 6, l15 = lane & 15, lk = lane >> 4;
    const int tt0  = blockIdx.x * tiles_per_block;

    floatx4 pv[8];
    auto issueP = [&](int tile) {
        const float* src = flat + (long)tile * 16384 + tid * 4;
        #pragma unroll
        for (int i = 0; i < 8; ++i) pv[i] = *(const floatx4*)(src + i * 2048);
    };
    issueP(tt0);

    const short8* wsv = (const short8*)wswz;

    for (int t = 0; t < tiles_per_block; ++t) {
        const int tile = tt0 + t;
        const int row0 = tile * 64;
        if (t) __syncthreads();                       // (a) store phase done

        if (tid < 64) flg[tid] = inv[row0 + tid];

        // ---- U loads first (deeper latency), 16 thr/row, 2 row-passes ----
        const int r16 = tid >> 4, se = tid & 15;
        const int symA = inv[row0 + r16];             // rows 0..31 (L1-hot)
        const int symB = inv[row0 + 32 + r16];        // rows 32..63
        floatx4 uva[4], uvb[4];
        if (symA > 0) {
            const float* ur = syms + (long)(symA - 1) * 256;
            #pragma unroll
            for (int i = 0; i < 4; ++i)
                uva[i] = *(const floatx4*)(ur + (i * 16 + se) * 4);
        }
        if (symB > 0) {
            const float* ur = syms + (long)(symB - 1) * 256;
            #pragma unroll
            for (int i = 0; i < 4; ++i)
                uvb[i] = *(const floatx4*)(ur + (i * 16 + se) * 4);
        }

        // ---- P: convert prefetched regs -> LDS (wave writes full rows) ----
        #pragma unroll
        for (int i = 0; i < 8; ++i) {
            const int f  = tid + i * 512;             // float4 idx in tile
            const int rr = f >> 6;                    // row (uniform per wave)
            const int gi = f & 63;                    // 16B granule
            const int cb = gi >> 1, hf = gi & 1;
            *(short4v*)&P[rr * 256 + ((cb ^ (rr & 7)) << 3) + hf * 4] = pack4(pv[i]);
        }
        // ---- U converts ----
        if (symA > 0) {
            #pragma unroll
            for (int i = 0; i < 4; ++i) {
                const int gi = i * 16 + se, cb = gi >> 1, hf = gi & 1;
                *(short4v*)&U[r16 * 256 + ((cb ^ (r16 & 7)) << 3) + hf * 4] = pack4(uva[i]);
            }
        }
        if (symB > 0) {
            const int rr = 32 + r16;
            #pragma unroll
            for (int i = 0; i < 4; ++i) {
                const int gi = i * 16 + se, cb = gi >> 1, hf = gi & 1;
                *(short4v*)&U[rr * 256 + ((cb ^ (rr & 7)) << 3) + hf * 4] = pack4(uvb[i]);
            }
        }
        __syncthreads();                              // (b) tile ready

        if (t + 1 < tiles_per_block) issueP(tile + 1);   // prefetch under GEMM

        // ---- K=512 MFMA ----
        floatx4 acc[4][4];   // [mi][c: 0,1=forget, 2,3=add]
        #pragma unroll
        for (int mi = 0; mi < 4; ++mi)
            #pragma unroll
            for (int c = 0; c < 4; ++c)
                acc[mi][c] = (floatx4){0.f, 0.f, 0.f, 0.f};

        #pragma unroll
        for (int ks = 0; ks < 16; ++ks) {
            short8 cb2[4];
            #pragma unroll
            for (int mi = 0; mi < 4; ++mi) {
                const int m = mi * 16 + l15;
                cb2[mi] = (ks < 8)
                    ? *(const short8*)&P[m * 256 + (((ks * 4 + lk) ^ (m & 7)) << 3)]
                    : *(const short8*)&U[m * 256 + ((((ks - 8) * 4 + lk) ^ (m & 7)) << 3)];
            }
            #pragma unroll
            for (int c = 0; c < 4; ++c) {
                const int g = (c < 2) ? (w * 2 + c) : (16 + w * 2 + (c - 2));
                const short8 wf = wsv[(g * 16 + ks) * 64 + lane];
                #pragma unroll
                for (int mi = 0; mi < 4; ++mi)
                    acc[mi][c] = __builtin_amdgcn_mfma_f32_16x16x32_bf16(
                        wf, cb2[mi], acc[mi][c], 0, 0, 0);
            }
        }
        __syncthreads();                              // (c) GEMM reads done

        // ---- combine: flagged lanes only; in-place bf16 into P ----
        #pragma unroll
        for (int c = 0; c < 2; ++c) {
            const int d0 = w * 32 + c * 16 + lk * 4;
            const floatx4 bfv = *(const floatx4*)(bfb + d0);
            const floatx4 bav = *(const floatx4*)(bab + d0);
            #pragma unroll
            for (int mi = 0; mi < 4; ++mi) {
                const int m = mi * 16 + l15;
                if (flg[m] > 0) {
                    const int sw = m & 7;
                    const int slot = (((d0 >> 3) ^ sw) << 3) + (d0 & 7);
                    short4v pvv = *(const short4v*)&P[m * 256 + slot];
                    short4v uvv = *(const short4v*)&U[m * 256 + slot];
                    floatx4 res;
                    #pragma unroll
                    for (int j = 0; j < 4; ++j) {
                        float fg = sigmoidf(acc[mi][c][j]     + bfv[j]);
                        float ag = sigmoidf(acc[mi][c + 2][j] + bav[j]);
                        res[j] = fg * bf2f((unsigned short)pvv[j])
                               + ag * bf2f((unsigned short)uvv[j]);
                    }
                    *(short4v*)&P[m * 256 + slot] = pack4(res);
                }
            }
        }
        __syncthreads();                              // (d) combined ready

        // ---- store: wave w rows w*8..w*8+7, full 1KB streams ----
        #pragma unroll
        for (int i = 0; i < 8; ++i) {
            const int rr = w * 8 + i;
            short4v s = *(const short4v*)
                &P[rr * 256 + (((lane >> 1) ^ (rr & 7)) << 3) + (lane & 1) * 4];
            floatx4 o4;
            o4[0] = bf2f((unsigned short)s[0]);
            o4[1] = bf2f((unsigned short)s[1]);
            o4[2] = bf2f((unsigned short)s[2]);
            o4[3] = bf2f((unsigned short)s[3]);
            *(floatx4*)(out + (long)(row0 + rr) * 256 + lane * 4) = o4;
        }
    }
}

extern "C" void kernel_launch(void* const* d_in, const int* in_sizes, int n_in,
                              void* d_out, int out_size, void* d_ws, size_t ws_size,
                              hipStream_t stream) {
    const float* flat = (const float*)d_in[0];
    const float* syms = (const float*)d_in[1];
    const float* Wf   = (const float*)d_in[2];
    const float* bf   = (const float*)d_in[3];
    const float* Wa   = (const float*)d_in[4];
    const float* ba   = (const float*)d_in[5];
    const int* ei     = (const int*)d_in[6];
    const int* ti     = (const int*)d_in[7];
    const int* si     = (const int*)d_in[8];
    float* out        = (float*)d_out;

    short* wswz = (short*)d_ws;                       // 512 KB
    int*   inv  = (int*)((char*)d_ws + 512 * 1024);   // 1 MB

    const int n_occ = in_sizes[6];        // 131072
    const int nrows = out_size / 256;     // 262144

    zero_inv_kernel<<<nrows / 256, 256, 0, stream>>>(inv);
    scatter_inv_kernel<<<(n_occ + 255) / 256, 256, 0, stream>>>(ei, ti, si,
                                                                inv, n_occ);
    convert_w_kernel<<<128, 256, 0, stream>>>(Wf, Wa, wswz);

    const int ntiles = nrows / 64;                    // 4096
    const int nblk   = 512;                           // 2 blocks/CU exactly
    const int tpb    = ntiles / nblk;                 // 8
    stream_kernel<<<nblk, 512, 0, stream>>>(flat, syms, bf, ba, inv, wswz,
                                            out, tpb);
}

// Round 11
// 352.542 us; speedup vs baseline: 2.2883x; 2.2883x over previous
//
#include <hip/hip_runtime.h>

typedef __attribute__((ext_vector_type(8))) short short8;
typedef __attribute__((ext_vector_type(4))) short short4v;
typedef __attribute__((ext_vector_type(2))) unsigned int uint2v;
typedef __attribute__((ext_vector_type(4))) float floatx4;

__device__ __forceinline__ unsigned short f2bf(float f) {
    unsigned int u = __float_as_uint(f);
    u += 0x7FFFu + ((u >> 16) & 1u);   // round-to-nearest-even
    return (unsigned short)(u >> 16);
}
__device__ __forceinline__ float bf2f(unsigned short s) {
    return __uint_as_float(((unsigned int)s) << 16);
}
__device__ __forceinline__ float sigmoidf(float x) {
    return 1.f / (1.f + __expf(-x));
}
// RTNE f32x4 -> bf16x4 via v_cvt_pk_bf16_f32 (no builtin; validated R10)
__device__ __forceinline__ short4v pack4(floatx4 v) {
    unsigned int a, b;
    asm("v_cvt_pk_bf16_f32 %0, %1, %2" : "=v"(a) : "v"(v[0]), "v"(v[1]));
    asm("v_cvt_pk_bf16_f32 %0, %1, %2" : "=v"(b) : "v"(v[2]), "v"(v[3]));
    uint2v u; u[0] = a; u[1] = b;
    return __builtin_bit_cast(short4v, u);
}

// Wf|Wa fp32 [256,512] -> bf16, MFMA A-operand fragment order (R8 layout).
// short8 idx = (g*16 + ks)*64 + lane; lane slot lk*16+l15 holds
// W[d = g*16+l15][k = ks*32+lk*8 .. +8].  g<16 -> Wf, g>=16 -> Wa.
__global__ __launch_bounds__(256)
void convert_w_kernel(const float* __restrict__ Wf,
                      const float* __restrict__ Wa,
                      short* __restrict__ wswz)
{
    int id = blockIdx.x * 256 + threadIdx.x;       // 32768 total
    int slot = id & 63;
    int ks   = (id >> 6) & 15;
    int g    = id >> 10;
    int l15  = slot & 15, lk = slot >> 4;
    const float* base = (g < 16) ? (Wf + (long)(g * 16 + l15) * 512)
                                 : (Wa + (long)((g - 16) * 16 + l15) * 512);
    const float* src = base + ks * 32 + lk * 8;
    floatx4 w0 = *(const floatx4*)src;
    floatx4 w1 = *(const floatx4*)(src + 4);
    short8 o;
    o[0] = (short)f2bf(w0[0]); o[1] = (short)f2bf(w0[1]);
    o[2] = (short)f2bf(w0[2]); o[3] = (short)f2bf(w0[3]);
    o[4] = (short)f2bf(w1[0]); o[5] = (short)f2bf(w1[1]);
    o[6] = (short)f2bf(w1[2]); o[7] = (short)f2bf(w1[3]);
    *(short8*)(wswz + (long)id * 8) = o;
}

__global__ __launch_bounds__(256)
void zero_flags_kernel(unsigned int* __restrict__ flags)   // 256 KB
{
    flags[blockIdx.x * 256 + threadIdx.x] = 0u;
}

__global__ __launch_bounds__(256)
void mark_kernel(const int* __restrict__ ei, const int* __restrict__ ti,
                 unsigned char* __restrict__ flags, int n)
{
    int i = blockIdx.x * 256 + threadIdx.x;
    if (i < n) flags[64 * ei[i] + ti[i]] = 1;
}

// Copy rows NOT updated (one wave per row; wave-uniform flag branch).
__global__ __launch_bounds__(256)
void copy_rest_kernel(const float* __restrict__ flat,
                      const unsigned char* __restrict__ flags,
                      float* __restrict__ out, int nrows)
{
    const int lane = threadIdx.x & 63;
    const int w0   = (blockIdx.x * 256 + threadIdx.x) >> 6;
    const int nw   = (gridDim.x * 256) >> 6;
    for (int row = w0; row < nrows; row += nw) {
        if (flags[row]) continue;
        const floatx4* s = (const floatx4*)(flat + (long)row * 256);
        floatx4*       o = (floatx4*)(out + (long)row * 256);
        o[lane] = s[lane];
    }
}

// Fused gather + bf16 GEMM + gates + combine + full-row scatter, with an
// INTRA-TILE 2-PHASE PIPELINE:
//   issue upd loads (oldest in VMEM queue), then prev loads;
//   stage upd (vmcnt waits only upd group) -> barrier ->
//   GEMM on upd K-half (ks 8..15)  [prev HBM loads land underneath] ->
//   stage prev -> barrier -> GEMM on prev K-half (ks 0..7).
// Everything else is the proven R8 structure: chunk^=(row&7) LDS swizzle,
// in-LDS combine, contiguous 1KB full-row stores (no write-allocate).
// Block: 512 thr (8 waves), 64 occ rows. LDS = P[32KB] + U[32KB].
__global__ __launch_bounds__(512, 4)
void gate_kernel(const float* __restrict__ flat,   // [262144,256]
                 const float* __restrict__ syms,   // [20000,256]
                 const float* __restrict__ bfb,
                 const float* __restrict__ bab,
                 const int* __restrict__ ei,
                 const int* __restrict__ ti,
                 const int* __restrict__ si,
                 const short* __restrict__ wswz,
                 float* __restrict__ out)
{
    __shared__ __align__(16) short P[64 * 256];   // prev bf16, 32 KB
    __shared__ __align__(16) short U[64 * 256];   // upd  bf16, 32 KB

    const int tid  = threadIdx.x;
    const int lane = tid & 63;
    const int w    = tid >> 6;     // wave 0..7
    const int occ0 = blockIdx.x * 64;
    const int l15  = lane & 15;
    const int lk   = lane >> 4;

    // ---- indices for this wave's 8 rows (wave-uniform -> scalar loads) ----
    int rowi[8], symi[8];
    #pragma unroll
    for (int i = 0; i < 8; ++i) {
        const int occ = occ0 + w * 8 + i;
        rowi[i] = 64 * ei[occ] + ti[occ];
        symi[i] = si[occ];
    }

    // ---- issue UPD loads first (oldest -> vmcnt can retire them alone) ----
    floatx4 uv[8];
    #pragma unroll
    for (int i = 0; i < 8; ++i)
        uv[i] = *(const floatx4*)(syms + (long)symi[i] * 256 + lane * 4);
    // ---- then PREV loads (newest; keep flying through the upd-half GEMM) --
    floatx4 pv[8];
    #pragma unroll
    for (int i = 0; i < 8; ++i)
        pv[i] = *(const floatx4*)(flat + (long)rowi[i] * 256 + lane * 4);

    // ---- stage upd: wave writes one full 512B row per inst (even banks) ---
    const int cb = lane >> 1, hf = lane & 1;
    #pragma unroll
    for (int i = 0; i < 8; ++i) {
        const int r = w * 8 + i;
        *(short4v*)&U[r * 256 + ((cb ^ (r & 7)) << 3) + hf * 4] = pack4(uv[i]);
    }
    __syncthreads();                               // #1: U tile ready

    floatx4 acc[4][4];   // [mi][c: 0,1=forget, 2,3=add]
    #pragma unroll
    for (int mi = 0; mi < 4; ++mi)
        #pragma unroll
        for (int c = 0; c < 4; ++c)
            acc[mi][c] = (floatx4){0.f, 0.f, 0.f, 0.f};

    const short8* wsv = (const short8*)wswz;

    // ---- GEMM upd half: ks_global 8..15 (prev loads land underneath) ----
    __builtin_amdgcn_s_setprio(1);
    #pragma unroll
    for (int ks = 0; ks < 8; ++ks) {
        short8 cb2[4];
        #pragma unroll
        for (int mi = 0; mi < 4; ++mi) {
            const int m  = mi * 16 + l15;
            const int ch = (ks * 4 + lk) ^ (m & 7);
            cb2[mi] = *(const short8*)&U[m * 256 + (ch << 3)];
        }
        #pragma unroll
        for (int c = 0; c < 4; ++c) {
            const int g = (c < 2) ? (w * 2 + c) : (16 + w * 2 + (c - 2));
            const short8 wf = wsv[(g * 16 + 8 + ks) * 64 + lane];
            #pragma unroll
            for (int mi = 0; mi < 4; ++mi)
                acc[mi][c] = __builtin_amdgcn_mfma_f32_16x16x32_bf16(
                    wf, cb2[mi], acc[mi][c], 0, 0, 0);
        }
    }
    __builtin_amdgcn_s_setprio(0);

    // ---- stage prev (vmcnt(0); should be resident by now) ----
    #pragma unroll
    for (int i = 0; i < 8; ++i) {
        const int r = w * 8 + i;
        *(short4v*)&P[r * 256 + ((cb ^ (r & 7)) << 3) + hf * 4] = pack4(pv[i]);
    }
    __syncthreads();                               // #2: P tile ready

    // ---- GEMM prev half: ks_global 0..7 ----
    __builtin_amdgcn_s_setprio(1);
    #pragma unroll
    for (int ks = 0; ks < 8; ++ks) {
        short8 cb2[4];
        #pragma unroll
        for (int mi = 0; mi < 4; ++mi) {
            const int m  = mi * 16 + l15;
            const int ch = (ks * 4 + lk) ^ (m & 7);
            cb2[mi] = *(const short8*)&P[m * 256 + (ch << 3)];
        }
        #pragma unroll
        for (int c = 0; c < 4; ++c) {
            const int g = (c < 2) ? (w * 2 + c) : (16 + w * 2 + (c - 2));
            const short8 wf = wsv[(g * 16 + ks) * 64 + lane];
            #pragma unroll
            for (int mi = 0; mi < 4; ++mi)
                acc[mi][c] = __builtin_amdgcn_mfma_f32_16x16x32_bf16(
                    wf, cb2[mi], acc[mi][c], 0, 0, 0);
        }
    }
    __builtin_amdgcn_s_setprio(0);
    __syncthreads();                               // #3: all P reads done

    // ---- combine in-place into P (bf16), lane owns (m, d0..d0+3) ----
    #pragma unroll
    for (int c = 0; c < 2; ++c) {
        const int d0 = w * 32 + c * 16 + lk * 4;
        const floatx4 bfv = *(const floatx4*)(bfb + d0);
        const floatx4 bav = *(const floatx4*)(bab + d0);
        #pragma unroll
        for (int mi = 0; mi < 4; ++mi) {
            const int m  = mi * 16 + l15;
            const int sw = m & 7;
            const int slot = (((d0 >> 3) ^ sw) << 3) + (d0 & 7);
            short4v pvv = *(const short4v*)&P[m * 256 + slot];
            short4v uvv = *(const short4v*)&U[m * 256 + slot];
            floatx4 res;
            #pragma unroll
            for (int j = 0; j < 4; ++j) {
                float fg = sigmoidf(acc[mi][c][j]     + bfv[j]);
                float ag = sigmoidf(acc[mi][c + 2][j] + bav[j]);
                res[j] = fg * bf2f((unsigned short)pvv[j])
                       + ag * bf2f((unsigned short)uvv[j]);
            }
            *(short4v*)&P[m * 256 + slot] = pack4(res);
        }
    }
    __syncthreads();                               // #4: combined rows ready

    // ---- full-row stores: wave w writes its rows w*8..w*8+7, 1KB each ----
    #pragma unroll
    for (int i = 0; i < 8; ++i) {
        const int rr = w * 8 + i;
        short4v s = *(const short4v*)
            &P[rr * 256 + (((lane >> 1) ^ (rr & 7)) << 3) + (lane & 1) * 4];
        floatx4 o4;
        o4[0] = bf2f((unsigned short)s[0]);
        o4[1] = bf2f((unsigned short)s[1]);
        o4[2] = bf2f((unsigned short)s[2]);
        o4[3] = bf2f((unsigned short)s[3]);
        *(floatx4*)(out + (long)rowi[i] * 256 + lane * 4) = o4;
    }
}

extern "C" void kernel_launch(void* const* d_in, const int* in_sizes, int n_in,
                              void* d_out, int out_size, void* d_ws, size_t ws_size,
                              hipStream_t stream) {
    const float* flat = (const float*)d_in[0];
    const float* syms = (const float*)d_in[1];
    const float* Wf   = (const float*)d_in[2];
    const float* bf   = (const float*)d_in[3];
    const float* Wa   = (const float*)d_in[4];
    const float* ba   = (const float*)d_in[5];
    const int* ei     = (const int*)d_in[6];
    const int* ti     = (const int*)d_in[7];
    const int* si     = (const int*)d_in[8];
    float* out        = (float*)d_out;

    short* wswz          = (short*)d_ws;                        // 512 KB
    unsigned char* flags = (unsigned char*)d_ws + 512 * 1024;   // 256 KB

    const int n_occ = in_sizes[6];        // 131072
    const int nrows = out_size / 256;     // 262144

    zero_flags_kernel<<<nrows / 1024, 256, 0, stream>>>((unsigned int*)flags);
    mark_kernel<<<(n_occ + 255) / 256, 256, 0, stream>>>(ei, ti, flags, n_occ);
    convert_w_kernel<<<128, 256, 0, stream>>>(Wf, Wa, wswz);

    gate_kernel<<<n_occ / 64, 512, 0, stream>>>(flat, syms, bf, ba,
                                                ei, ti, si, wswz, out);

    copy_rest_kernel<<<2048, 256, 0, stream>>>(flat, flags, out, nrows);
}